// Round 1
// 8000.708 us; speedup vs baseline: 1.6991x; 1.6991x over previous
//
#include <hip/hip_runtime.h>
#include <cmath>

// Problem constants (B, T, H) = (128, 1024, 512), fp32 throughout.
#define B_ 128
#define T_ 1024
#define H_ 512

// ---------------------------------------------------------------------------
// Phase 1: out[t,b,:] = X[b,t,:] @ Wx + bias   (fully parallel GEMM)
// M = B*T = 131072 rows (m = b*1024 + t), N = K = 512.
// 64x64 tile per block, 256 threads, 4x4 accumulators per thread, K-chunk 16.
// Writes directly into d_out at row (t*128 + b) -> phase 2 updates in place.
// ---------------------------------------------------------------------------
__global__ __launch_bounds__(256) void xw_gemm(const float* __restrict__ X,
                                               const float* __restrict__ Wx,
                                               const float* __restrict__ bias,
                                               float* __restrict__ out) {
  const int m0 = blockIdx.x * 64;
  const int n0 = blockIdx.y * 64;

  __shared__ float As[16][64];  // [k][m]
  __shared__ float Bs[16][64];  // [k][n]

  const int tid = threadIdx.x;
  const int ti = tid >> 4;  // 0..15 (m sub-tile)
  const int tj = tid & 15;  // 0..15 (n sub-tile)

  // staging assignments
  const int ra = tid >> 2;         // 0..63   (A row within tile)
  const int ca = (tid & 3) << 2;   // 0,4,8,12 (A k within chunk, float4)
  const int kb = tid >> 4;         // 0..15   (B k within chunk)
  const int nb = (tid & 15) << 2;  // 0..60   (B col within tile, float4)

  float acc[4][4] = {};

  for (int k0 = 0; k0 < H_; k0 += 16) {
    // stage A tile (64 m x 16 k), transposed into As[k][m]
    const float4 a4 =
        *reinterpret_cast<const float4*>(X + (size_t)(m0 + ra) * H_ + k0 + ca);
    As[ca + 0][ra] = a4.x;
    As[ca + 1][ra] = a4.y;
    As[ca + 2][ra] = a4.z;
    As[ca + 3][ra] = a4.w;
    // stage B tile (16 k x 64 n), direct
    *reinterpret_cast<float4*>(&Bs[kb][nb]) =
        *reinterpret_cast<const float4*>(Wx + (size_t)(k0 + kb) * H_ + n0 + nb);
    __syncthreads();

#pragma unroll
    for (int kk = 0; kk < 16; ++kk) {
      const float4 a = *reinterpret_cast<const float4*>(&As[kk][ti << 2]);
      const float4 b = *reinterpret_cast<const float4*>(&Bs[kk][tj << 2]);
      acc[0][0] = fmaf(a.x, b.x, acc[0][0]);
      acc[0][1] = fmaf(a.x, b.y, acc[0][1]);
      acc[0][2] = fmaf(a.x, b.z, acc[0][2]);
      acc[0][3] = fmaf(a.x, b.w, acc[0][3]);
      acc[1][0] = fmaf(a.y, b.x, acc[1][0]);
      acc[1][1] = fmaf(a.y, b.y, acc[1][1]);
      acc[1][2] = fmaf(a.y, b.z, acc[1][2]);
      acc[1][3] = fmaf(a.y, b.w, acc[1][3]);
      acc[2][0] = fmaf(a.z, b.x, acc[2][0]);
      acc[2][1] = fmaf(a.z, b.y, acc[2][1]);
      acc[2][2] = fmaf(a.z, b.z, acc[2][2]);
      acc[2][3] = fmaf(a.z, b.w, acc[2][3]);
      acc[3][0] = fmaf(a.w, b.x, acc[3][0]);
      acc[3][1] = fmaf(a.w, b.y, acc[3][1]);
      acc[3][2] = fmaf(a.w, b.z, acc[3][2]);
      acc[3][3] = fmaf(a.w, b.w, acc[3][3]);
    }
    __syncthreads();
  }

  const float4 bv =
      *reinterpret_cast<const float4*>(bias + n0 + (tj << 2));
#pragma unroll
  for (int ii = 0; ii < 4; ++ii) {
    const int m = m0 + (ti << 2) + ii;
    const int b = m >> 10;    // m / 1024
    const int t = m & 1023;   // m % 1024
    float4 v;
    v.x = acc[ii][0] + bv.x;
    v.y = acc[ii][1] + bv.y;
    v.z = acc[ii][2] + bv.z;
    v.w = acc[ii][3] + bv.w;
    *reinterpret_cast<float4*>(out + ((size_t)t * B_ + b) * H_ + n0 +
                               (tj << 2)) = v;
  }
}

// ---------------------------------------------------------------------------
// Phase 2 (NEW): persistent weight-stationary recurrence across all 256 CUs.
//
// Grid = 256 WGs = NRG(64 row-groups of 2 batch rows) x NCG(4 col-groups of
// 128 cols). Each WG holds its Wh slice [512 k][128 j] in VGPRs (float2
// w[64] per thread = 128 regs, loaded once) and stays resident for all 1024
// steps. Per step:
//   - lane l of wave kc holds h[2 rows] at k = kc*64+l (2 coalesced loads
//     from out[t-1] / state0)
//   - fully unrolled k-loop: 2 v_readlane broadcasts + 4 FMAs per k
//     (no LDS, no Wh traffic in the hot loop)
//   - 8-wave partial sums reduced via 8 KB LDS scratch, tanh, store out[t]
//   - cross-WG handoff: release atomicAdd (agent scope) on flag[t][rg];
//     consumers spin relaxed + one acquire fence. bid = cg*64+rg keeps a
//     row-group's 4 WGs on one XCD under the bid%8 round-robin heuristic
//     (perf only; correctness is agent-scope).
//
// Deadlock-safe by construction: grid(256) <= guaranteed residency capacity
// (>=1 WG/CU x 256 CUs: 512 thr, 8 KB LDS, <=256 VGPR), and each WG releases
// step t before waiting on step t. Flags zeroed by in-graph hipMemsetAsync.
// ---------------------------------------------------------------------------
#define NRG 64
#define NCG 4
#define FLAG_BYTES (T_ * NRG * sizeof(int))

__device__ __forceinline__ float rl(float v, int i) {
  return __int_as_float(__builtin_amdgcn_readlane(__float_as_int(v), i));
}

__global__ __launch_bounds__(512) void rnn_recurrence_p(
    const float* __restrict__ state0, const float* __restrict__ Wh,
    float* __restrict__ out, int* __restrict__ flags) {
  __shared__ float scratch[8 * 2 * 128];  // [kc][r][j]

  const int tid = threadIdx.x;
  const int kc = tid >> 6;         // wave id 0..7 -> k-chunk of 64
  const int lane = tid & 63;
  const int rg = blockIdx.x & (NRG - 1);
  const int cg = blockIdx.x >> 6;
  const int b0 = rg * 2;
  const int j0 = cg * 128 + 2 * lane;  // this thread's two output columns
  const int kbase = kc * 64;

  // Wh slice into registers: w[i] = Wh[kbase+i][j0 .. j0+1]  (128 VGPRs)
  float2 w[64];
#pragma unroll
  for (int i = 0; i < 64; ++i)
    w[i] = *reinterpret_cast<const float2*>(Wh + (size_t)(kbase + i) * H_ + j0);

  // reduce-phase mapping (threads 0..255): row rr, local col jj
  const int rr = tid >> 7;
  const int jj = tid & 127;
  const size_t ro = (size_t)(b0 + rr) * H_ + cg * 128 + jj;

  // per-lane h addresses (k = kbase + lane)
  const size_t h0off = (size_t)b0 * H_ + kbase + lane;
  const size_t h1off = h0off + H_;

  for (int t = 0; t < T_; ++t) {
    float* outt = out + (size_t)t * (B_ * H_);

    // prefetch pre-activation (phase-1 output; independent of the flag wait)
    float pre = 0.f;
    if (tid < 256) pre = outt[ro];

    if (t > 0) {
      if (tid == 0) {
        while (__hip_atomic_load(&flags[(t - 1) * NRG + rg], __ATOMIC_RELAXED,
                                 __HIP_MEMORY_SCOPE_AGENT) < NCG) {
        }
        __builtin_amdgcn_fence(__ATOMIC_ACQUIRE, "agent");
      }
      __syncthreads();  // also protects LDS scratch reuse (WAR vs reduce)
    }

    const float* hprev = (t == 0) ? state0 : (outt - (size_t)(B_ * H_));
    const float h0 = hprev[h0off];
    const float h1 = hprev[h1off];

    float a00 = 0.f, a01 = 0.f, a10 = 0.f, a11 = 0.f;
#pragma unroll
    for (int i = 0; i < 64; ++i) {
      const float s0 = rl(h0, i);  // h[b0  ][kbase+i], broadcast via SGPR
      const float s1 = rl(h1, i);  // h[b0+1][kbase+i]
      a00 = fmaf(w[i].x, s0, a00);
      a01 = fmaf(w[i].y, s0, a01);
      a10 = fmaf(w[i].x, s1, a10);
      a11 = fmaf(w[i].y, s1, a11);
    }

    // cross-wave reduction scratch: [kc][r][j]
    *reinterpret_cast<float2*>(&scratch[kc * 256 + 2 * lane]) =
        make_float2(a00, a01);
    *reinterpret_cast<float2*>(&scratch[kc * 256 + 128 + 2 * lane]) =
        make_float2(a10, a11);
    __syncthreads();

    if (tid < 256) {
      float s = pre;
#pragma unroll
      for (int q = 0; q < 8; ++q) s += scratch[q * 256 + rr * 128 + jj];
      outt[ro] = tanhf(s);
    }
    __syncthreads();  // drain out[] stores (vmcnt) before the release

    if (tid == 0)
      __hip_atomic_fetch_add(&flags[t * NRG + rg], 1, __ATOMIC_RELEASE,
                             __HIP_MEMORY_SCOPE_AGENT);
  }
}

// ---------------------------------------------------------------------------
// Phase 2 (fallback, previous version): used only if the workspace is too
// small to hold the sync flags. 64 WGs, sequential in-place recurrence.
// ---------------------------------------------------------------------------
__global__ __launch_bounds__(512) void rnn_recurrence(
    const float* __restrict__ state0, const float* __restrict__ Wh,
    float* __restrict__ out) {
  const int j = threadIdx.x;       // output column 0..511
  const int b0 = blockIdx.x * 2;   // batch rows owned by this WG
  const int b1 = b0 + 1;

  __shared__ float2 hh[H_];  // (h[b0][k], h[b1][k])

  hh[j] = make_float2(state0[(size_t)b0 * H_ + j], state0[(size_t)b1 * H_ + j]);
  __syncthreads();

  const float* __restrict__ wp = Wh + j;  // column j, stride H_ over k

  for (int t = 0; t < T_; ++t) {
    float* o0 = out + (size_t)t * (B_ * H_) + (size_t)b0 * H_ + j;
    float* o1 = o0 + H_;
    float acc0 = *o0;  // precomputed x@Wx + b
    float acc1 = *o1;

#pragma unroll 8
    for (int k = 0; k < H_; ++k) {
      const float2 h2 = hh[k];
      const float w = wp[(size_t)k * H_];
      acc0 = fmaf(h2.x, w, acc0);
      acc1 = fmaf(h2.y, w, acc1);
    }

    const float v0 = tanhf(acc0);
    const float v1 = tanhf(acc1);

    __syncthreads();  // all k-loop reads of hh done before overwrite
    hh[j] = make_float2(v0, v1);
    *o0 = v0;
    *o1 = v1;
    __syncthreads();  // new h visible before next step's reads
  }
}

extern "C" void kernel_launch(void* const* d_in, const int* in_sizes, int n_in,
                              void* d_out, int out_size, void* d_ws,
                              size_t ws_size, hipStream_t stream) {
  const float* X     = (const float*)d_in[0];  // [B, T, H]
  const float* state = (const float*)d_in[1];  // [1, B, H] (zeros)
  const float* Wx    = (const float*)d_in[2];  // [H, H]
  const float* Wh    = (const float*)d_in[3];  // [H, H]
  const float* bias  = (const float*)d_in[4];  // [H]
  float* out = (float*)d_out;                  // [T, B, H]

  // Phase 1: M/64 = 2048 tiles x N/64 = 8 tiles
  hipLaunchKernelGGL(xw_gemm, dim3(2048, 8), dim3(256), 0, stream, X, Wx, bias,
                     out);

  if (d_ws != nullptr && ws_size >= FLAG_BYTES) {
    // zero the per-(t, rg) flag counters (captured in the graph each launch)
    hipMemsetAsync(d_ws, 0, FLAG_BYTES, stream);
    hipLaunchKernelGGL(rnn_recurrence_p, dim3(NRG * NCG), dim3(512), 0, stream,
                       state, Wh, out, (int*)d_ws);
  } else {
    // fallback: previous sequential-per-CU version
    hipLaunchKernelGGL(rnn_recurrence, dim3(64), dim3(512), 0, stream, state,
                       Wh, out);
  }
}

// Round 3
// 7998.631 us; speedup vs baseline: 1.6995x; 1.0003x over previous
//
#include <hip/hip_runtime.h>
#include <cmath>

// Problem constants (B, T, H) = (128, 1024, 512), fp32 throughout.
#define B_ 128
#define T_ 1024
#define H_ 512

// ---------------------------------------------------------------------------
// Phase 1: out[t,b,:] = X[b,t,:] @ Wx + bias   (fully parallel GEMM)
// 64x64 tile per block, 256 threads, 4x4 accumulators per thread, K-chunk 16.
// Writes directly into d_out at row (t*128 + b) -> phase 2 updates in place.
// (Unchanged; ~1.0 ms vs 437 us fp32-vector roofline — target after phase 2.)
// ---------------------------------------------------------------------------
__global__ __launch_bounds__(256) void xw_gemm(const float* __restrict__ X,
                                               const float* __restrict__ Wx,
                                               const float* __restrict__ bias,
                                               float* __restrict__ out) {
  const int m0 = blockIdx.x * 64;
  const int n0 = blockIdx.y * 64;

  __shared__ float As[16][64];  // [k][m]
  __shared__ float Bs[16][64];  // [k][n]

  const int tid = threadIdx.x;
  const int ti = tid >> 4;  // 0..15 (m sub-tile)
  const int tj = tid & 15;  // 0..15 (n sub-tile)

  const int ra = tid >> 2;         // 0..63   (A row within tile)
  const int ca = (tid & 3) << 2;   // 0,4,8,12 (A k within chunk, float4)
  const int kb = tid >> 4;         // 0..15   (B k within chunk)
  const int nb = (tid & 15) << 2;  // 0..60   (B col within tile, float4)

  float acc[4][4] = {};

  for (int k0 = 0; k0 < H_; k0 += 16) {
    const float4 a4 =
        *reinterpret_cast<const float4*>(X + (size_t)(m0 + ra) * H_ + k0 + ca);
    As[ca + 0][ra] = a4.x;
    As[ca + 1][ra] = a4.y;
    As[ca + 2][ra] = a4.z;
    As[ca + 3][ra] = a4.w;
    *reinterpret_cast<float4*>(&Bs[kb][nb]) =
        *reinterpret_cast<const float4*>(Wx + (size_t)(k0 + kb) * H_ + n0 + nb);
    __syncthreads();

#pragma unroll
    for (int kk = 0; kk < 16; ++kk) {
      const float4 a = *reinterpret_cast<const float4*>(&As[kk][ti << 2]);
      const float4 b = *reinterpret_cast<const float4*>(&Bs[kk][tj << 2]);
      acc[0][0] = fmaf(a.x, b.x, acc[0][0]);
      acc[0][1] = fmaf(a.x, b.y, acc[0][1]);
      acc[0][2] = fmaf(a.x, b.z, acc[0][2]);
      acc[0][3] = fmaf(a.x, b.w, acc[0][3]);
      acc[1][0] = fmaf(a.y, b.x, acc[1][0]);
      acc[1][1] = fmaf(a.y, b.y, acc[1][1]);
      acc[1][2] = fmaf(a.y, b.z, acc[1][2]);
      acc[1][3] = fmaf(a.y, b.w, acc[1][3]);
      acc[2][0] = fmaf(a.z, b.x, acc[2][0]);
      acc[2][1] = fmaf(a.z, b.y, acc[2][1]);
      acc[2][2] = fmaf(a.z, b.z, acc[2][2]);
      acc[2][3] = fmaf(a.z, b.w, acc[2][3]);
      acc[3][0] = fmaf(a.w, b.x, acc[3][0]);
      acc[3][1] = fmaf(a.w, b.y, acc[3][1]);
      acc[3][2] = fmaf(a.w, b.z, acc[3][2]);
      acc[3][3] = fmaf(a.w, b.w, acc[3][3]);
    }
    __syncthreads();
  }

  const float4 bv =
      *reinterpret_cast<const float4*>(bias + n0 + (tj << 2));
#pragma unroll
  for (int ii = 0; ii < 4; ++ii) {
    const int m = m0 + (ti << 2) + ii;
    const int b = m >> 10;    // m / 1024
    const int t = m & 1023;   // m % 1024
    float4 v;
    v.x = acc[ii][0] + bv.x;
    v.y = acc[ii][1] + bv.y;
    v.z = acc[ii][2] + bv.z;
    v.w = acc[ii][3] + bv.w;
    *reinterpret_cast<float4*>(out + ((size_t)t * B_ + b) * H_ + n0 +
                               (tj << 2)) = v;
  }
}

// ---------------------------------------------------------------------------
// Phase 2 v3: persistent weight-stationary recurrence with ROUND-1's PROVEN
// release/acquire handoff (round 2's fence-free scheme read stale h on HW:
// vmcnt-drain does NOT imply IC visibility of relaxed agent stores).
//
// Grid = 256 WGs = NRG(64 rg of 2 batch rows) x NCG(4 cg of 128 cols),
// bid = cg*64+rg. Each WG holds its Wh slice [512 k][128 j] in VGPRs
// (float2 w[64] = 128 regs). __launch_bounds__(512, 2) raises the VGPR
// budget to 256 so the slice actually STAYS resident — round 1's
// VGPR_Count=72 proved the default budget sank the loads into the t-loop,
// re-streaming 128 KB/step/CU; that, not the fences per se, was the 6.9 ms.
//
// Handoff (identical to the round-1 kernel that passed):
//   producer: plain out[] stores -> __syncthreads (drains vmcnt) ->
//             tid0 atomicAdd RELEASE agent on flags[t][rg]  (writes back
//             dirty L2 so peers can see the out[] stores)
//   consumer: tid0 spins RELAXED until counter == NCG -> ACQUIRE agent
//             fence (invalidates stale cache lines) -> __syncthreads ->
//             plain loads of h from out[t-1]
// The 2 waves whose k-chunk is self-produced read h from LDS (hloc,
// barrier-ordered) instead of global — no ordering involvement.
//
// Deadlock-safe: grid(256) <= 1 WG/CU x 256 CUs guaranteed residency
// (512 thr, 9.25 KB LDS, <=256 VGPR => 2 waves/SIMD), and each WG releases
// step t before waiting on step t. Flags zeroed by in-graph hipMemsetAsync.
// ---------------------------------------------------------------------------
#define NRG 64
#define NCG 4
#define FLAG_BYTES (T_ * NRG * sizeof(int))

__device__ __forceinline__ float rl(float v, int i) {
  return __int_as_float(__builtin_amdgcn_readlane(__float_as_int(v), i));
}

__global__ __launch_bounds__(512, 2) void rnn_recurrence_p3(
    const float* __restrict__ state0, const float* __restrict__ Wh,
    float* __restrict__ out, int* __restrict__ flags) {
  __shared__ float scratch[8 * 2 * 128];  // [kc][r][jj] partial sums
  __shared__ float hloc[2 * 128];         // this WG's own h slice [r][jj]

  const int tid = threadIdx.x;
  const int kc = tid >> 6;   // wave id 0..7 -> k-chunk of 64
  const int lane = tid & 63;
  const int rg = blockIdx.x & (NRG - 1);
  const int cg = blockIdx.x >> 6;
  const int b0 = rg * 2;
  const int j0 = cg * 128 + 2 * lane;  // this thread's two output columns
  const int kbase = kc * 64;
  const int src_cg = kbase >> 7;       // producer col-group of my k-chunk
  const bool self = (src_cg == cg);    // my h chunk comes from my own WG

  // Wh slice into registers (128 VGPRs), pinned before the t-loop.
  float2 w[64];
#pragma unroll
  for (int i = 0; i < 64; ++i)
    w[i] = *reinterpret_cast<const float2*>(Wh + (size_t)(kbase + i) * H_ + j0);
  asm volatile("" ::: "memory");  // forbid sinking the w loads into the loop

  // reduce-phase mapping (threads 0..255): row rr, local col jj
  const int rr = tid >> 7;
  const int jj = tid & 127;
  const size_t ro = (size_t)(b0 + rr) * H_ + cg * 128 + jj;

  const int myk = kbase + lane;  // h element this lane loads (per row)
  const size_t h0off = (size_t)b0 * H_ + myk;
  const size_t h1off = h0off + H_;

  for (int t = 0; t < T_; ++t) {
    float* outt = out + (size_t)t * (B_ * H_);

    // prefetch pre-activation (phase-1 output; this WG is its only writer)
    float pre = 0.f;
    if (tid < 256) pre = outt[ro];

    if (t > 0) {
      if (tid == 0) {
        while (__hip_atomic_load(&flags[(t - 1) * NRG + rg], __ATOMIC_RELAXED,
                                 __HIP_MEMORY_SCOPE_AGENT) < NCG) {
        }
        __builtin_amdgcn_fence(__ATOMIC_ACQUIRE, "agent");
      }
      __syncthreads();  // broadcast spin result; also scratch/hloc WAR guard
    }

    float h0, h1;
    if (t == 0) {
      h0 = state0[h0off];
      h1 = state0[h1off];
    } else if (self) {
      // own WG's step t-1 output, barrier-ordered in LDS
      h0 = hloc[myk - cg * 128];
      h1 = hloc[128 + (myk - cg * 128)];
    } else {
      const float* hprev = outt - (size_t)(B_ * H_);
      h0 = hprev[h0off];
      h1 = hprev[h1off];
    }

    float a00 = 0.f, a01 = 0.f, a10 = 0.f, a11 = 0.f;
#pragma unroll
    for (int i = 0; i < 64; ++i) {
      const float s0 = rl(h0, i);  // h[b0  ][kbase+i] via SGPR broadcast
      const float s1 = rl(h1, i);  // h[b0+1][kbase+i]
      a00 = fmaf(w[i].x, s0, a00);
      a01 = fmaf(w[i].y, s0, a01);
      a10 = fmaf(w[i].x, s1, a10);
      a11 = fmaf(w[i].y, s1, a11);
    }

    // cross-wave reduction scratch: [kc][r][jj]
    *reinterpret_cast<float2*>(&scratch[kc * 256 + 2 * lane]) =
        make_float2(a00, a01);
    *reinterpret_cast<float2*>(&scratch[kc * 256 + 128 + 2 * lane]) =
        make_float2(a10, a11);
    __syncthreads();

    if (tid < 256) {
      float s = pre;
#pragma unroll
      for (int q = 0; q < 8; ++q) s += scratch[q * 256 + rr * 128 + jj];
      const float v = tanhf(s);
      outt[ro] = v;             // h_t, read by partner WGs next step
      hloc[rr * 128 + jj] = v;  // self-feed for the 2 self waves
    }
    __syncthreads();  // drain vmcnt for ALL waves before the release

    if (tid == 0)
      __hip_atomic_fetch_add(&flags[t * NRG + rg], 1, __ATOMIC_RELEASE,
                             __HIP_MEMORY_SCOPE_AGENT);
  }
}

// ---------------------------------------------------------------------------
// Phase 2 fallback: sequential in-place recurrence (no workspace needed).
// ---------------------------------------------------------------------------
__global__ __launch_bounds__(512) void rnn_recurrence(
    const float* __restrict__ state0, const float* __restrict__ Wh,
    float* __restrict__ out) {
  const int j = threadIdx.x;
  const int b0 = blockIdx.x * 2;
  const int b1 = b0 + 1;

  __shared__ float2 hh[H_];

  hh[j] = make_float2(state0[(size_t)b0 * H_ + j], state0[(size_t)b1 * H_ + j]);
  __syncthreads();

  const float* __restrict__ wp = Wh + j;

  for (int t = 0; t < T_; ++t) {
    float* o0 = out + (size_t)t * (B_ * H_) + (size_t)b0 * H_ + j;
    float* o1 = o0 + H_;
    float acc0 = *o0;
    float acc1 = *o1;

#pragma unroll 8
    for (int k = 0; k < H_; ++k) {
      const float2 h2 = hh[k];
      const float w = wp[(size_t)k * H_];
      acc0 = fmaf(h2.x, w, acc0);
      acc1 = fmaf(h2.y, w, acc1);
    }

    const float v0 = tanhf(acc0);
    const float v1 = tanhf(acc1);

    __syncthreads();
    hh[j] = make_float2(v0, v1);
    *o0 = v0;
    *o1 = v1;
    __syncthreads();
  }
}

extern "C" void kernel_launch(void* const* d_in, const int* in_sizes, int n_in,
                              void* d_out, int out_size, void* d_ws,
                              size_t ws_size, hipStream_t stream) {
  const float* X     = (const float*)d_in[0];  // [B, T, H]
  const float* state = (const float*)d_in[1];  // [1, B, H] (zeros)
  const float* Wx    = (const float*)d_in[2];  // [H, H]
  const float* Wh    = (const float*)d_in[3];  // [H, H]
  const float* bias  = (const float*)d_in[4];  // [H]
  float* out = (float*)d_out;                  // [T, B, H]

  hipLaunchKernelGGL(xw_gemm, dim3(2048, 8), dim3(256), 0, stream, X, Wx, bias,
                     out);

  if (d_ws != nullptr && ws_size >= FLAG_BYTES) {
    // zero the per-(t, rg) flag counters (graph-captured each launch)
    hipMemsetAsync(d_ws, 0, FLAG_BYTES, stream);
    hipLaunchKernelGGL(rnn_recurrence_p3, dim3(NRG * NCG), dim3(512), 0,
                       stream, state, Wh, out, (int*)d_ws);
  } else {
    hipLaunchKernelGGL(rnn_recurrence, dim3(64), dim3(512), 0, stream, state,
                       Wh, out);
  }
}

// Round 4
// 6999.190 us; speedup vs baseline: 1.9422x; 1.1428x over previous
//
#include <hip/hip_runtime.h>
#include <cmath>

// Problem constants (B, T, H) = (128, 1024, 512), fp32 throughout.
#define B_ 128
#define T_ 1024
#define H_ 512

// ---------------------------------------------------------------------------
// Phase 1: out[t,b,:] = X[b,t,:] @ Wx + bias   (fully parallel GEMM)
// 64x64 tile per block, 256 threads, 4x4 accumulators per thread, K-chunk 16.
// Writes directly into d_out at row (t*128 + b) -> phase 2 updates in place.
// (Unchanged; ~1.0 ms vs 437 us fp32-vector roofline — next target once the
//  recurrence is no longer dominant.)
// ---------------------------------------------------------------------------
__global__ __launch_bounds__(256) void xw_gemm(const float* __restrict__ X,
                                               const float* __restrict__ Wx,
                                               const float* __restrict__ bias,
                                               float* __restrict__ out) {
  const int m0 = blockIdx.x * 64;
  const int n0 = blockIdx.y * 64;

  __shared__ float As[16][64];  // [k][m]
  __shared__ float Bs[16][64];  // [k][n]

  const int tid = threadIdx.x;
  const int ti = tid >> 4;  // 0..15 (m sub-tile)
  const int tj = tid & 15;  // 0..15 (n sub-tile)

  const int ra = tid >> 2;         // 0..63   (A row within tile)
  const int ca = (tid & 3) << 2;   // 0,4,8,12 (A k within chunk, float4)
  const int kb = tid >> 4;         // 0..15   (B k within chunk)
  const int nb = (tid & 15) << 2;  // 0..60   (B col within tile, float4)

  float acc[4][4] = {};

  for (int k0 = 0; k0 < H_; k0 += 16) {
    const float4 a4 =
        *reinterpret_cast<const float4*>(X + (size_t)(m0 + ra) * H_ + k0 + ca);
    As[ca + 0][ra] = a4.x;
    As[ca + 1][ra] = a4.y;
    As[ca + 2][ra] = a4.z;
    As[ca + 3][ra] = a4.w;
    *reinterpret_cast<float4*>(&Bs[kb][nb]) =
        *reinterpret_cast<const float4*>(Wx + (size_t)(k0 + kb) * H_ + n0 + nb);
    __syncthreads();

#pragma unroll
    for (int kk = 0; kk < 16; ++kk) {
      const float4 a = *reinterpret_cast<const float4*>(&As[kk][ti << 2]);
      const float4 b = *reinterpret_cast<const float4*>(&Bs[kk][tj << 2]);
      acc[0][0] = fmaf(a.x, b.x, acc[0][0]);
      acc[0][1] = fmaf(a.x, b.y, acc[0][1]);
      acc[0][2] = fmaf(a.x, b.z, acc[0][2]);
      acc[0][3] = fmaf(a.x, b.w, acc[0][3]);
      acc[1][0] = fmaf(a.y, b.x, acc[1][0]);
      acc[1][1] = fmaf(a.y, b.y, acc[1][1]);
      acc[1][2] = fmaf(a.y, b.z, acc[1][2]);
      acc[1][3] = fmaf(a.y, b.w, acc[1][3]);
      acc[2][0] = fmaf(a.z, b.x, acc[2][0]);
      acc[2][1] = fmaf(a.z, b.y, acc[2][1]);
      acc[2][2] = fmaf(a.z, b.z, acc[2][2]);
      acc[2][3] = fmaf(a.z, b.w, acc[2][3]);
      acc[3][0] = fmaf(a.w, b.x, acc[3][0]);
      acc[3][1] = fmaf(a.w, b.y, acc[3][1]);
      acc[3][2] = fmaf(a.w, b.z, acc[3][2]);
      acc[3][3] = fmaf(a.w, b.w, acc[3][3]);
    }
    __syncthreads();
  }

  const float4 bv =
      *reinterpret_cast<const float4*>(bias + n0 + (tj << 2));
#pragma unroll
  for (int ii = 0; ii < 4; ++ii) {
    const int m = m0 + (ti << 2) + ii;
    const int b = m >> 10;    // m / 1024
    const int t = m & 1023;   // m % 1024
    float4 v;
    v.x = acc[ii][0] + bv.x;
    v.y = acc[ii][1] + bv.y;
    v.z = acc[ii][2] + bv.z;
    v.w = acc[ii][3] + bv.w;
    *reinterpret_cast<float4*>(out + ((size_t)t * B_ + b) * H_ + n0 +
                               (tj << 2)) = v;
  }
}

// ---------------------------------------------------------------------------
// Phase 2 v4: persistent weight-stationary recurrence.
//
// Changes vs round 3 (which timed identical to round 1 at 6.9 ms):
//  (1) REAL weight pin. Round-3's operand-less `asm ::: "memory"` couldn't
//      pin loads from a noalias const pointer (alias analysis sees the asm
//      can't touch Wh -> loads sunk into the loop; VGPR_Count=80 proved it).
//      Now each loaded value is passed through asm("" : "+v"(x)) — the
//      values become asm outputs, non-rematerializable, and must stay in
//      VGPRs (budget 256 via __launch_bounds__(512,2)).
//  (2) NO consumer acquire fence. Round 1/3's per-step ACQUIRE agent fence
//      emits buffer_inv (invalidates the CU's entire L1+L2 each step ->
//      forced w/out/flag refetch from IC chip-wide). Instead consumers read
//      the 3 KB of non-self h via RELAXED AGENT atomic loads, which bypass
//      local caches and read the coherence point (IC). Freshness is
//      guaranteed by the PRODUCER side, unchanged and proven in rounds 1/3:
//      fetch_add RELEASE agent = vmcnt drain + buffer_wbl2 (pushes the
//      plain h stores to IC) + IC-executed add. Flag visible => h at IC.
//      (Our own measurements prove relaxed agent loads see IC updates: the
//      round-1/3 spin observes the flag BEFORE any acquire fence runs.)
//      h addresses are fresh each step, so consumer caches never hold them.
//
// Grid = 256 WGs = NRG(64 rg of 2 batch rows) x NCG(4 cg of 128 cols),
// bid = cg*64+rg. Deadlock-safe: 256 WGs <= 1 WG/CU x 256 CUs guaranteed
// residency (512 thr, 9.25 KB LDS, <=256 VGPR => 2 waves/SIMD), and each WG
// releases step t before waiting on step t. Flags zeroed via hipMemsetAsync.
// ---------------------------------------------------------------------------
#define NRG 64
#define NCG 4
#define FLAG_BYTES (T_ * NRG * sizeof(int))

__device__ __forceinline__ float rl(float v, int i) {
  return __int_as_float(__builtin_amdgcn_readlane(__float_as_int(v), i));
}

__global__ __launch_bounds__(512, 2) void rnn_recurrence_p4(
    const float* __restrict__ state0, const float* __restrict__ Wh,
    float* __restrict__ out, int* __restrict__ flags) {
  __shared__ float scratch[8 * 2 * 128];  // [kc][r][jj] partial sums
  __shared__ float hloc[2 * 128];         // this WG's own h slice [r][jj]

  const int tid = threadIdx.x;
  const int kc = tid >> 6;   // wave id 0..7 -> k-chunk of 64
  const int lane = tid & 63;
  const int rg = blockIdx.x & (NRG - 1);
  const int cg = blockIdx.x >> 6;
  const int b0 = rg * 2;
  const int j0 = cg * 128 + 2 * lane;  // this thread's two output columns
  const int kbase = kc * 64;
  const int src_cg = kbase >> 7;       // producer col-group of my k-chunk
  const bool self = (src_cg == cg);    // my h chunk comes from my own WG

  // Wh slice into registers (128 VGPRs).
  float2 w[64];
#pragma unroll
  for (int i = 0; i < 64; ++i)
    w[i] = *reinterpret_cast<const float2*>(Wh + (size_t)(kbase + i) * H_ + j0);
  // Pin the VALUES (not the memory): each becomes an asm output, which the
  // compiler cannot rematerialize as a load inside the t-loop.
#pragma unroll
  for (int i = 0; i < 64; ++i)
    asm volatile("" : "+v"(w[i].x), "+v"(w[i].y));

  // reduce-phase mapping (threads 0..255): row rr, local col jj
  const int rr = tid >> 7;
  const int jj = tid & 127;
  const size_t ro = (size_t)(b0 + rr) * H_ + cg * 128 + jj;

  const int myk = kbase + lane;  // h element this lane loads (per row)
  const size_t h0off = (size_t)b0 * H_ + myk;
  const size_t h1off = h0off + H_;

  for (int t = 0; t < T_; ++t) {
    float* outt = out + (size_t)t * (B_ * H_);

    // prefetch pre-activation (phase-1 output; this WG is its only writer)
    float pre = 0.f;
    if (tid < 256) pre = outt[ro];

    if (t > 0) {
      if (tid == 0) {
        while (__hip_atomic_load(&flags[(t - 1) * NRG + rg], __ATOMIC_RELAXED,
                                 __HIP_MEMORY_SCOPE_AGENT) < NCG) {
        }
      }
      __syncthreads();  // broadcast spin result; also scratch/hloc WAR guard
    }

    float h0, h1;
    if (t == 0) {
      h0 = state0[h0off];
      h1 = state0[h1off];
    } else if (self) {
      // own WG's step t-1 output, barrier-ordered in LDS
      h0 = hloc[myk - cg * 128];
      h1 = hloc[128 + (myk - cg * 128)];
    } else {
      // bypassing loads straight from the coherence point (IC); fresh
      // because the producer's RELEASE fetch_add wrote h back before the
      // flag became visible, and these addresses were never cached here.
      const float* hprev = outt - (size_t)(B_ * H_);
      h0 = __hip_atomic_load(hprev + h0off, __ATOMIC_RELAXED,
                             __HIP_MEMORY_SCOPE_AGENT);
      h1 = __hip_atomic_load(hprev + h1off, __ATOMIC_RELAXED,
                             __HIP_MEMORY_SCOPE_AGENT);
    }

    float a00 = 0.f, a01 = 0.f, a10 = 0.f, a11 = 0.f;
#pragma unroll
    for (int i = 0; i < 64; ++i) {
      const float s0 = rl(h0, i);  // h[b0  ][kbase+i] via SGPR broadcast
      const float s1 = rl(h1, i);  // h[b0+1][kbase+i]
      a00 = fmaf(w[i].x, s0, a00);
      a01 = fmaf(w[i].y, s0, a01);
      a10 = fmaf(w[i].x, s1, a10);
      a11 = fmaf(w[i].y, s1, a11);
    }

    // cross-wave reduction scratch: [kc][r][jj]
    *reinterpret_cast<float2*>(&scratch[kc * 256 + 2 * lane]) =
        make_float2(a00, a01);
    *reinterpret_cast<float2*>(&scratch[kc * 256 + 128 + 2 * lane]) =
        make_float2(a10, a11);
    __syncthreads();

    if (tid < 256) {
      float s = pre;
#pragma unroll
      for (int q = 0; q < 8; ++q) s += scratch[q * 256 + rr * 128 + jj];
      const float v = tanhf(s);
      outt[ro] = v;             // h_t, read by partner WGs next step
      hloc[rr * 128 + jj] = v;  // self-feed for the 2 self waves
    }
    __syncthreads();  // drain vmcnt for ALL waves before the release

    // RELEASE agent: vmcnt drain + buffer_wbl2 (h stores -> IC) + IC add.
    if (tid == 0)
      __hip_atomic_fetch_add(&flags[t * NRG + rg], 1, __ATOMIC_RELEASE,
                             __HIP_MEMORY_SCOPE_AGENT);
  }
}

// ---------------------------------------------------------------------------
// Phase 2 fallback: sequential in-place recurrence (no workspace needed).
// ---------------------------------------------------------------------------
__global__ __launch_bounds__(512) void rnn_recurrence(
    const float* __restrict__ state0, const float* __restrict__ Wh,
    float* __restrict__ out) {
  const int j = threadIdx.x;
  const int b0 = blockIdx.x * 2;
  const int b1 = b0 + 1;

  __shared__ float2 hh[H_];

  hh[j] = make_float2(state0[(size_t)b0 * H_ + j], state0[(size_t)b1 * H_ + j]);
  __syncthreads();

  const float* __restrict__ wp = Wh + j;

  for (int t = 0; t < T_; ++t) {
    float* o0 = out + (size_t)t * (B_ * H_) + (size_t)b0 * H_ + j;
    float* o1 = o0 + H_;
    float acc0 = *o0;
    float acc1 = *o1;

#pragma unroll 8
    for (int k = 0; k < H_; ++k) {
      const float2 h2 = hh[k];
      const float w = wp[(size_t)k * H_];
      acc0 = fmaf(h2.x, w, acc0);
      acc1 = fmaf(h2.y, w, acc1);
    }

    const float v0 = tanhf(acc0);
    const float v1 = tanhf(acc1);

    __syncthreads();
    hh[j] = make_float2(v0, v1);
    *o0 = v0;
    *o1 = v1;
    __syncthreads();
  }
}

extern "C" void kernel_launch(void* const* d_in, const int* in_sizes, int n_in,
                              void* d_out, int out_size, void* d_ws,
                              size_t ws_size, hipStream_t stream) {
  const float* X     = (const float*)d_in[0];  // [B, T, H]
  const float* state = (const float*)d_in[1];  // [1, B, H] (zeros)
  const float* Wx    = (const float*)d_in[2];  // [H, H]
  const float* Wh    = (const float*)d_in[3];  // [H, H]
  const float* bias  = (const float*)d_in[4];  // [H]
  float* out = (float*)d_out;                  // [T, B, H]

  hipLaunchKernelGGL(xw_gemm, dim3(2048, 8), dim3(256), 0, stream, X, Wx, bias,
                     out);

  if (d_ws != nullptr && ws_size >= FLAG_BYTES) {
    // zero the per-(t, rg) flag counters (graph-captured each launch)
    hipMemsetAsync(d_ws, 0, FLAG_BYTES, stream);
    hipLaunchKernelGGL(rnn_recurrence_p4, dim3(NRG * NCG), dim3(512), 0,
                       stream, state, Wh, out, (int*)d_ws);
  } else {
    hipLaunchKernelGGL(rnn_recurrence, dim3(64), dim3(512), 0, stream, state,
                       Wh, out);
  }
}